// Round 1
// baseline (175.289 us; speedup 1.0000x reference)
//
#include <hip/hip_runtime.h>

#pragma clang fp contract(off)

#define NBOX 8192
#define BLK  1024
#define NBUCK 2048
#define IOU_THR 0.1f

typedef unsigned int u32;
typedef unsigned long long u64;

__global__ __launch_bounds__(BLK) void nms_kernel(const float* __restrict__ in,
                                                  float* __restrict__ out) {
    const int img = blockIdx.x;
    const float* __restrict__ p = in + (size_t)img * 5 * NBOX;
    float* __restrict__ o = out + (size_t)img * 5 * NBOX;
    const int t = threadIdx.x;
    const int lane = t & 63;
    const int wid = t >> 6;

    __shared__ u64 skey[NBOX];          // 64 KB: high32 = ~orderable(score), low32 = idx
    __shared__ u32 hist[NBUCK];         // 8 KB
    __shared__ u32 bbase[NBUCK];        // 8 KB
    __shared__ u32 bcur[NBUCK];         // 8 KB
    __shared__ u32 kom[NBOX / 32];      // 1 KB keep-original bitmask
    __shared__ u32 pfx[NBOX / 32];      // 1 KB
    __shared__ float kx1[64], ky1[64], kx2[64], ky2[64], kar[64];
    __shared__ int wsum[BLK / 64];
    __shared__ int S0_sh, nk_sh;

    // ---- init ----
    for (int i = t; i < NBUCK; i += BLK) hist[i] = 0;
    for (int i = t; i < NBOX / 32; i += BLK) kom[i] = 0;
    if (t == 0) S0_sh = 0;
    __syncthreads();

    // ---- pass 1: histogram by value-bucket (uniform scores -> balanced) ----
    u32 mybucket[8];
    for (int e = 0; e < 8; e++) {
        int j = t + e * BLK;
        float s = p[4 * NBOX + j];
        int vb = (int)(s * (float)NBUCK);
        vb = vb < 0 ? 0 : (vb > NBUCK - 1 ? NBUCK - 1 : vb);
        int b = NBUCK - 1 - vb;          // monotone decreasing in score
        mybucket[e] = (u32)b;
        atomicAdd(&hist[b], 1u);
    }
    __syncthreads();

    // ---- exclusive scan over hist (2 bins / thread) ----
    {
        u32 h0 = hist[2 * t], h1 = hist[2 * t + 1];
        int v = (int)(h0 + h1);
        int x = v;
        for (int d = 1; d < 64; d <<= 1) {
            int y = __shfl_up(x, d, 64);
            if (lane >= d) x += y;
        }
        if (lane == 63) wsum[wid] = x;
        __syncthreads();
        int wb = 0;
        for (int i = 0; i < wid; i++) wb += wsum[i];
        int excl = wb + x - v;
        bbase[2 * t] = (u32)excl;
        bbase[2 * t + 1] = (u32)excl + h0;
        bcur[2 * t] = (u32)excl;
        bcur[2 * t + 1] = (u32)excl + h0;
    }
    __syncthreads();

    // ---- pass 2: scatter keys into bucket regions ----
    for (int e = 0; e < 8; e++) {
        int j = t + e * BLK;
        float s = p[4 * NBOX + j];
        u32 u = __float_as_uint(s);
        u32 ordb = u ^ (u32)(((int)u >> 31) | (int)0x80000000);  // ascending orderable
        u32 inv = ~ordb;                                         // ascending == score desc
        u32 pos = atomicAdd(&bcur[mybucket[e]], 1u);
        skey[pos] = ((u64)inv << 32) | (u32)j;
    }
    __syncthreads();

    // ---- per-bucket insertion sort (keys distinct: idx embedded) ----
    for (int b = t; b < NBUCK; b += BLK) {
        int lo = (int)bbase[b];
        int hi = lo + (int)hist[b];
        for (int i = lo + 1; i < hi; i++) {
            u64 x = skey[i];
            int j2 = i - 1;
            while (j2 >= lo && skey[j2] > x) { skey[j2 + 1] = skey[j2]; j2--; }
            skey[j2 + 1] = x;
        }
    }
    __syncthreads();

    // ---- extract sorted idx (alias u32 over skey), count score>0 ----
    u32 myidx[8];
    int vcnt = 0;
    for (int e = 0; e < 8; e++) {
        u64 k = skey[t * 8 + e];
        myidx[e] = (u32)k;
        if ((u32)(k >> 32) < 0x7FFFFFFFu) vcnt++;  // score > 0
    }
    __syncthreads();
    u32* sidx = (u32*)skey;
    for (int e = 0; e < 8; e++) sidx[t * 8 + e] = myidx[e];
    atomicAdd(&S0_sh, vcnt);
    __syncthreads();

    int S = S0_sh;

    // ---- batched greedy NMS over compacted, sorted survivor list ----
    while (S > 0) {
        int nb = S < 64 ? S : 64;

        if (wid == 0) {
            int j = -1;
            float x1 = 0, y1 = 0, x2 = 0, y2 = 0, ar = 0;
            int alive = 0;
            if (lane < nb) {
                j = (int)sidx[lane];
                float cx = p[0 * NBOX + j], cy = p[1 * NBOX + j];
                float w = p[2 * NBOX + j], h = p[3 * NBOX + j];
                x1 = cx - w * 0.5f; y1 = cy - h * 0.5f;
                x2 = cx + w * 0.5f; y2 = cy + h * 0.5f;
                ar = (x2 - x1) * (y2 - y1);
                alive = 1;
            }
            for (int l = 0; l < nb; l++) {
                u64 m = __ballot(alive);
                if ((m >> l) & 1ull) {
                    float bx1 = __shfl(x1, l, 64), by1 = __shfl(y1, l, 64);
                    float bx2 = __shfl(x2, l, 64), by2 = __shfl(y2, l, 64);
                    float bar = __shfl(ar, l, 64);
                    if (lane > l && alive) {
                        float iw = fminf(x2, bx2) - fmaxf(x1, bx1); iw = fmaxf(iw, 0.0f);
                        float ih = fminf(y2, by2) - fmaxf(y1, by1); ih = fmaxf(ih, 0.0f);
                        float inter = iw * ih;
                        float uni = bar + ar - inter;
                        float iou = inter / (uni + 1e-8f);
                        if (iou >= IOU_THR) alive = 0;
                    }
                }
            }
            u64 m = __ballot(alive);
            if (alive) {
                int q = (int)__popcll(m & ((1ull << lane) - 1ull));
                kx1[q] = x1; ky1[q] = y1; kx2[q] = x2; ky2[q] = y2; kar[q] = ar;
                atomicOr(&kom[j >> 5], 1u << (j & 31));
            }
            if (lane == 0) nk_sh = (int)__popcll(m);
        }
        __syncthreads();

        int nk = nk_sh;
        int tail = S - nb;
        int C = (tail + BLK - 1) / BLK;
        u32 sv[8];
        int mloc = 0;
        int st = nb + t * C;
        int en = st + C; if (en > S) en = S;
        for (int pos2 = st; pos2 < en; pos2++) {
            int j = (int)sidx[pos2];
            float cx = p[0 * NBOX + j], cy = p[1 * NBOX + j];
            float w = p[2 * NBOX + j], h = p[3 * NBOX + j];
            float x1 = cx - w * 0.5f, y1 = cy - h * 0.5f;
            float x2 = cx + w * 0.5f, y2 = cy + h * 0.5f;
            float ar = (x2 - x1) * (y2 - y1);
            bool ok = true;
            for (int c = 0; c < nk; c++) {
                float iw = fminf(x2, kx2[c]) - fmaxf(x1, kx1[c]); iw = fmaxf(iw, 0.0f);
                float ih = fminf(y2, ky2[c]) - fmaxf(y1, ky1[c]); ih = fmaxf(ih, 0.0f);
                float inter = iw * ih;
                float uni = kar[c] + ar - inter;
                float iou = inter / (uni + 1e-8f);
                if (iou >= IOU_THR) { ok = false; break; }
            }
            if (ok) sv[mloc++] = (u32)j;
        }
        // block scan to compact survivors (all reads above complete before barrier)
        {
            int x = mloc;
            for (int d = 1; d < 64; d <<= 1) {
                int y = __shfl_up(x, d, 64);
                if (lane >= d) x += y;
            }
            if (lane == 63) wsum[wid] = x;
            __syncthreads();
            int wb = 0, tot = 0;
            for (int i = 0; i < BLK / 64; i++) {
                int v = wsum[i];
                if (i < wid) wb += v;
                tot += v;
            }
            int off = wb + x - mloc;
            for (int q = 0; q < mloc; q++) sidx[off + q] = sv[q];
            __syncthreads();
            S = tot;
        }
    }

    // ---- output: prefix popcount over keep bitmask, zero + scatter ----
    if (t == 0) {
        u32 run = 0;
        for (int i = 0; i < NBOX / 32; i++) { pfx[i] = run; run += (u32)__popc(kom[i]); }
    }
    __syncthreads();
    float4 z4; z4.x = z4.y = z4.z = z4.w = 0.0f;
    float4* o4 = (float4*)o;
    for (int i = t; i < 5 * NBOX / 4; i += BLK) o4[i] = z4;
    __syncthreads();
    for (int j = t; j < NBOX; j += BLK) {
        u32 km = kom[j >> 5];
        if ((km >> (j & 31)) & 1u) {
            int pos2 = (int)(pfx[j >> 5] + (u32)__popc(km & ((1u << (j & 31)) - 1u)));
            for (int r = 0; r < 5; r++) o[r * NBOX + pos2] = p[r * NBOX + j];
        }
    }
}

extern "C" void kernel_launch(void* const* d_in, const int* in_sizes, int n_in,
                              void* d_out, int out_size, void* d_ws, size_t ws_size,
                              hipStream_t stream) {
    const float* in = (const float*)d_in[0];
    float* out = (float*)d_out;
    int B = in_sizes[0] / (5 * NBOX);
    hipLaunchKernelGGL(nms_kernel, dim3(B), dim3(BLK), 0, stream, in, out);
}